// Round 11
// baseline (1477.177 us; speedup 1.0000x reference)
//
#include <hip/hip_runtime.h>
#include <math.h>

#define N_NODES 100000
#define E_EDGES 1600000
#define S_SNAP  4
#define D_IN    128
#define H_DIM   256
#define P_POST  10000
#define N4 (S_SNAP * N_NODES)               // 400000
#define E4 (S_SNAP * E_EDGES)               // 6400000
#define NBLK4 ((N4 + 1023) / 1024)          // 391 (scan block = 1024 elems, int4/thread)
#define NBIN 8
#define BIN_W (N_NODES / NBIN)              // 12500 -> 50KB LDS histogram
#define C_CHUNK 16
#define EPC (E_EDGES / C_CHUNK)             // 100000 edges per chunk
#define PREP_BLOCKS (S_SNAP * NBIN * C_CHUNK)   // 512
#define ROWS_PER_BLK (BIN_W / 4)            // 3125

typedef __attribute__((ext_vector_type(8))) short bf16x8;   // MFMA A/B frag (4 VGPRs)
typedef __attribute__((ext_vector_type(4))) float f32x4;    // MFMA C/D frag

// ---------- bf16 helpers ----------
__device__ __forceinline__ float bf2f(unsigned short u) {
    union { unsigned int i; float f; } v; v.i = ((unsigned int)u) << 16; return v.f;
}
__device__ __forceinline__ unsigned short f2bf(float f) {
    union { float f; unsigned int i; } v; v.f = f;
    unsigned int lsb = (v.i >> 16) & 1u;
    v.i += 0x7fffu + lsb;                 // round-nearest-even
    return (unsigned short)(v.i >> 16);
}

// ---------------- utility ----------------
__global__ void zero32_kernel(unsigned int* __restrict__ p, int n) {
    int i = blockIdx.x * blockDim.x + threadIdx.x;
    if (i < n) p[i] = 0u;
}

// ---------------- atomic-free CSR build (LDS histograms; no global atomics) ----------------
// K1: block (s,bin,chunk) -> LDS histogram of its chunk's in-bin dsts; coalesced count write
__global__ __launch_bounds__(256) void count_kernel(const int* __restrict__ ei,
        int* __restrict__ counts) {
    __shared__ int cnt[BIN_W];
    for (int r = threadIdx.x; r < BIN_W; r += 256) cnt[r] = 0;
    __syncthreads();
    int bx = blockIdx.x;
    int c = bx & (C_CHUNK - 1);
    int b = (bx >> 4) & (NBIN - 1);
    int s = bx >> 7;
    int lo = b * BIN_W;
    const int* dstp = ei + (size_t)s * 2 * E_EDGES + E_EDGES;
    int j1 = (c + 1) * EPC;
    for (int j = c * EPC + threadIdx.x; j < j1; j += 256) {
        int d = dstp[j] - lo;
        if ((unsigned)d < BIN_W) atomicAdd(&cnt[d], 1);   // LDS atomic
    }
    __syncthreads();
    int* outp = counts + (size_t)bx * BIN_W;
    for (int r = threadIdx.x; r < BIN_W; r += 256) outp[r] = cnt[r];
}

// K2: per row, exclusive prefix over chunks (in place -> chunkbase), emit deg4
__global__ __launch_bounds__(256) void chunkprefix_kernel(int* __restrict__ counts,
        int* __restrict__ deg4) {
    int bx = blockIdx.x;                    // 128 blocks: (s, b, row-quarter)
    int rc = bx & 3;
    int b = (bx >> 2) & (NBIN - 1);
    int s = bx >> 5;
    size_t base = ((size_t)(s * NBIN + b) * C_CHUNK) * BIN_W;
    int r1 = (rc + 1) * ROWS_PER_BLK;
    for (int r = rc * ROWS_PER_BLK + threadIdx.x; r < r1; r += 256) {
        int run = 0;
        #pragma unroll
        for (int c = 0; c < C_CHUNK; ++c) {       // per-c access is lane-coalesced
            size_t idx = base + (size_t)c * BIN_W + r;
            int v = counts[idx];
            counts[idx] = run;                    // exclusive chunk prefix
            run += v;
        }
        deg4[s * N_NODES + b * BIN_W + r] = run;
    }
}

// scan phase 1 over deg4[4N]; also emits dinv4
__global__ __launch_bounds__(256) void scan_part4_kernel(const int* __restrict__ deg4,
        int* __restrict__ bsum, float* __restrict__ dinv4) {
    __shared__ int red[4];
    int base = blockIdx.x * 1024 + threadIdx.x * 4;
    int4 v = make_int4(0, 0, 0, 0);
    if (base < N4) {
        v = *(const int4*)(deg4 + base);
        dinv4[base + 0] = rsqrtf((float)(v.x + 1));   // +1 self-loop
        dinv4[base + 1] = rsqrtf((float)(v.y + 1));
        dinv4[base + 2] = rsqrtf((float)(v.z + 1));
        dinv4[base + 3] = rsqrtf((float)(v.w + 1));
    }
    int t = v.x + v.y + v.z + v.w;
    #pragma unroll
    for (int off = 32; off > 0; off >>= 1) t += __shfl_down(t, off, 64);
    int wave = threadIdx.x >> 6, lane = threadIdx.x & 63;
    if (lane == 0) red[wave] = t;
    __syncthreads();
    if (threadIdx.x == 0) bsum[blockIdx.x] = red[0] + red[1] + red[2] + red[3];
}

__global__ __launch_bounds__(512) void scan_top_kernel(const int* __restrict__ bsum,
        int* __restrict__ boff) {
    __shared__ int s[512];
    int t = threadIdx.x;
    s[t] = (t < NBLK4) ? bsum[t] : 0;
    __syncthreads();
    for (int off = 1; off < 512; off <<= 1) {
        int v = (t >= off) ? s[t - off] : 0;
        __syncthreads();
        s[t] += v;
        __syncthreads();
    }
    if (t < NBLK4) boff[t] = (t == 0) ? 0 : s[t - 1];
}

__global__ __launch_bounds__(256) void scan_fin4_kernel(const int* __restrict__ deg4,
        const int* __restrict__ boff, int* __restrict__ rowptr4) {
    __shared__ int sh[256];
    int base = blockIdx.x * 1024 + threadIdx.x * 4;
    int4 v = make_int4(0, 0, 0, 0);
    if (base < N4) v = *(const int4*)(deg4 + base);
    int tsum = v.x + v.y + v.z + v.w;
    sh[threadIdx.x] = tsum;
    __syncthreads();
    for (int off = 1; off < 256; off <<= 1) {
        int u = (threadIdx.x >= off) ? sh[threadIdx.x - off] : 0;
        __syncthreads();
        sh[threadIdx.x] += u;
        __syncthreads();
    }
    int excl = boff[blockIdx.x] + sh[threadIdx.x] - tsum;
    if (base < N4) {
        int4 o;
        o.x = excl;
        o.y = excl + v.x;
        o.z = excl + v.x + v.y;
        o.w = excl + v.x + v.y + v.z;
        *(int4*)(rowptr4 + base) = o;
    }
    if (base == 0) rowptr4[N4] = E4;
}

// K3: replay with LDS local slots; pos = rowptr + chunkbase + localslot (binned writes)
__global__ __launch_bounds__(256) void fillb_kernel(const int* __restrict__ ei,
        const int* __restrict__ counts, const int* __restrict__ rowptr4,
        int* __restrict__ csrsrc4) {
    __shared__ int cnt[BIN_W];
    for (int r = threadIdx.x; r < BIN_W; r += 256) cnt[r] = 0;
    __syncthreads();
    int bx = blockIdx.x;
    int c = bx & (C_CHUNK - 1);
    int b = (bx >> 4) & (NBIN - 1);
    int s = bx >> 7;
    int lo = b * BIN_W;
    const int* srcp = ei + (size_t)s * 2 * E_EDGES;
    const int* dstp = srcp + E_EDGES;
    const int* cb = counts + (size_t)bx * BIN_W;      // chunkbase region (hot, 50KB)
    const int* rp = rowptr4 + s * N_NODES + lo;       // hot 50KB window
    int j1 = (c + 1) * EPC;
    for (int j = c * EPC + threadIdx.x; j < j1; j += 256) {
        int d = dstp[j] - lo;
        if ((unsigned)d < BIN_W) {
            int ls = atomicAdd(&cnt[d], 1);           // LDS atomic
            csrsrc4[rp[d] + cb[d] + ls] = srcp[j];
        }
    }
}

// ------- MFMA GEMM (once per call): xw1 = x @ W1, bf16 out -------
// Layouts (HW-verified r8): A[m=lane&15][k=quad*8+j]; B[k][n=lane&15]; C/D col=lane&15,row=quad*4+reg
__global__ __launch_bounds__(256) void gemm_xw1_mfma(const float* __restrict__ A,
        const float* __restrict__ B, unsigned short* __restrict__ C, int M) {
    __shared__ unsigned short As[64][136];   // [m][k], +8 pad
    __shared__ unsigned short Bs[64][136];   // [n][k]
    int tid = threadIdx.x;
    int m0 = blockIdx.x * 64, n0 = blockIdx.y * 64;
    {
        int row = tid >> 2, c0 = (tid & 3) * 32;
        int gm = m0 + row;
        #pragma unroll
        for (int i = 0; i < 8; ++i) {
            float4 v = make_float4(0.f, 0.f, 0.f, 0.f);
            if (gm < M) v = *(const float4*)(A + (size_t)gm * D_IN + c0 + i * 4);
            As[row][c0 + i * 4 + 0] = f2bf(v.x);
            As[row][c0 + i * 4 + 1] = f2bf(v.y);
            As[row][c0 + i * 4 + 2] = f2bf(v.z);
            As[row][c0 + i * 4 + 3] = f2bf(v.w);
        }
    }
    {
        int k = tid >> 1, nb = (tid & 1) * 32;
        #pragma unroll
        for (int i = 0; i < 8; ++i) {
            float4 v = *(const float4*)(B + (size_t)k * H_DIM + n0 + nb + i * 4);
            Bs[nb + i * 4 + 0][k] = f2bf(v.x);
            Bs[nb + i * 4 + 1][k] = f2bf(v.y);
            Bs[nb + i * 4 + 2][k] = f2bf(v.z);
            Bs[nb + i * 4 + 3][k] = f2bf(v.w);
        }
    }
    __syncthreads();
    int w = tid >> 6, l = tid & 63;
    int q = l >> 4, mrow = l & 15;
    f32x4 acc[4] = {{0.f,0.f,0.f,0.f},{0.f,0.f,0.f,0.f},{0.f,0.f,0.f,0.f},{0.f,0.f,0.f,0.f}};
    #pragma unroll
    for (int kk = 0; kk < 4; ++kk) {
        bf16x8 a = *(const bf16x8*)&As[16 * w + mrow][kk * 32 + q * 8];
        #pragma unroll
        for (int ct = 0; ct < 4; ++ct) {
            bf16x8 b = *(const bf16x8*)&Bs[ct * 16 + mrow][kk * 32 + q * 8];
            acc[ct] = __builtin_amdgcn_mfma_f32_16x16x32_bf16(a, b, acc[ct], 0, 0, 0);
        }
    }
    #pragma unroll
    for (int ct = 0; ct < 4; ++ct) {
        int col = n0 + ct * 16 + mrow;
        #pragma unroll
        for (int i = 0; i < 4; ++i) {
            int m = m0 + 16 * w + q * 4 + i;
            if (m < M) C[(size_t)m * H_DIM + col] = f2bf(acc[ct][i]);
        }
    }
}

// ------- SpMM layer 0 (fused bias+relu), 4-way edge unroll (r7/r9-proven: VGPR 20) -------
__global__ __launch_bounds__(256) void spmm_l0_kernel(const unsigned short* __restrict__ xw1,
        const float* __restrict__ dinv4, const int* __restrict__ rowptr4,
        const int* __restrict__ csrsrc4, const float* __restrict__ b1,
        unsigned short* __restrict__ h, int soff) {
    int r = (blockIdx.x << 2) + (threadIdx.x >> 6);
    int lane = threadIdx.x & 63;
    int rg = soff + r;
    int e0 = rowptr4[rg], e1 = rowptr4[rg + 1];
    float di = dinv4[rg];
    float4 acc = make_float4(0.f, 0.f, 0.f, 0.f);
    const ushort4* tp = (const ushort4*)xw1;
    const float* dv = dinv4 + soff;
    int e = e0;
    for (; e + 4 <= e1; e += 4) {
        int s0 = csrsrc4[e], s1 = csrsrc4[e + 1], s2 = csrsrc4[e + 2], s3 = csrsrc4[e + 3];
        float w0 = dv[s0] * di, w1 = dv[s1] * di, w2 = dv[s2] * di, w3 = dv[s3] * di;
        ushort4 u0 = tp[(size_t)s0 * 64 + lane];
        ushort4 u1 = tp[(size_t)s1 * 64 + lane];
        ushort4 u2 = tp[(size_t)s2 * 64 + lane];
        ushort4 u3 = tp[(size_t)s3 * 64 + lane];
        acc.x = fmaf(bf2f(u0.x), w0, acc.x); acc.y = fmaf(bf2f(u0.y), w0, acc.y);
        acc.z = fmaf(bf2f(u0.z), w0, acc.z); acc.w = fmaf(bf2f(u0.w), w0, acc.w);
        acc.x = fmaf(bf2f(u1.x), w1, acc.x); acc.y = fmaf(bf2f(u1.y), w1, acc.y);
        acc.z = fmaf(bf2f(u1.z), w1, acc.z); acc.w = fmaf(bf2f(u1.w), w1, acc.w);
        acc.x = fmaf(bf2f(u2.x), w2, acc.x); acc.y = fmaf(bf2f(u2.y), w2, acc.y);
        acc.z = fmaf(bf2f(u2.z), w2, acc.z); acc.w = fmaf(bf2f(u2.w), w2, acc.w);
        acc.x = fmaf(bf2f(u3.x), w3, acc.x); acc.y = fmaf(bf2f(u3.y), w3, acc.y);
        acc.z = fmaf(bf2f(u3.z), w3, acc.z); acc.w = fmaf(bf2f(u3.w), w3, acc.w);
    }
    for (; e < e1; ++e) {
        int s = csrsrc4[e];
        float wv = dv[s] * di;
        ushort4 u = tp[(size_t)s * 64 + lane];
        acc.x = fmaf(bf2f(u.x), wv, acc.x); acc.y = fmaf(bf2f(u.y), wv, acc.y);
        acc.z = fmaf(bf2f(u.z), wv, acc.z); acc.w = fmaf(bf2f(u.w), wv, acc.w);
    }
    ushort4 us = tp[(size_t)r * 64 + lane];
    float wd = di * di;
    float4 bb = ((const float4*)b1)[lane];
    ushort4 o;
    o.x = f2bf(fmaxf(fmaf(bf2f(us.x), wd, acc.x) + bb.x, 0.f));
    o.y = f2bf(fmaxf(fmaf(bf2f(us.y), wd, acc.y) + bb.y, 0.f));
    o.z = f2bf(fmaxf(fmaf(bf2f(us.z), wd, acc.z) + bb.z, 0.f));
    o.w = f2bf(fmaxf(fmaf(bf2f(us.w), wd, acc.w) + bb.w, 0.f));
    ((ushort4*)h)[(size_t)r * 64 + lane] = o;
}

// ---------------- SpMM layer 1 (post rows only) ----------------
__global__ __launch_bounds__(256) void spmm_h_post_kernel(const unsigned short* __restrict__ h,
        const float* __restrict__ dinv4, const int* __restrict__ rowptr4,
        const int* __restrict__ csrsrc4, const int* __restrict__ post,
        float* __restrict__ t1p, int soff) {
    int p = (blockIdx.x << 2) + (threadIdx.x >> 6);
    int lane = threadIdx.x & 63;
    int r = post[p];
    int rg = soff + r;
    int e0 = rowptr4[rg], e1 = rowptr4[rg + 1];
    float di = dinv4[rg];
    float4 acc = make_float4(0.f, 0.f, 0.f, 0.f);
    const ushort4* hp = (const ushort4*)h;
    const float* dv = dinv4 + soff;
    int e = e0;
    for (; e + 4 <= e1; e += 4) {
        int s0 = csrsrc4[e], s1 = csrsrc4[e + 1], s2 = csrsrc4[e + 2], s3 = csrsrc4[e + 3];
        float w0 = dv[s0] * di, w1 = dv[s1] * di, w2 = dv[s2] * di, w3 = dv[s3] * di;
        ushort4 u0 = hp[(size_t)s0 * 64 + lane];
        ushort4 u1 = hp[(size_t)s1 * 64 + lane];
        ushort4 u2 = hp[(size_t)s2 * 64 + lane];
        ushort4 u3 = hp[(size_t)s3 * 64 + lane];
        acc.x = fmaf(bf2f(u0.x), w0, acc.x); acc.y = fmaf(bf2f(u0.y), w0, acc.y);
        acc.z = fmaf(bf2f(u0.z), w0, acc.z); acc.w = fmaf(bf2f(u0.w), w0, acc.w);
        acc.x = fmaf(bf2f(u1.x), w1, acc.x); acc.y = fmaf(bf2f(u1.y), w1, acc.y);
        acc.z = fmaf(bf2f(u1.z), w1, acc.z); acc.w = fmaf(bf2f(u1.w), w1, acc.w);
        acc.x = fmaf(bf2f(u2.x), w2, acc.x); acc.y = fmaf(bf2f(u2.y), w2, acc.y);
        acc.z = fmaf(bf2f(u2.z), w2, acc.z); acc.w = fmaf(bf2f(u2.w), w2, acc.w);
        acc.x = fmaf(bf2f(u3.x), w3, acc.x); acc.y = fmaf(bf2f(u3.y), w3, acc.y);
        acc.z = fmaf(bf2f(u3.z), w3, acc.z); acc.w = fmaf(bf2f(u3.w), w3, acc.w);
    }
    for (; e < e1; ++e) {
        int s = csrsrc4[e];
        float wv = dv[s] * di;
        ushort4 u = hp[(size_t)s * 64 + lane];
        acc.x = fmaf(bf2f(u.x), wv, acc.x); acc.y = fmaf(bf2f(u.y), wv, acc.y);
        acc.z = fmaf(bf2f(u.z), wv, acc.z); acc.w = fmaf(bf2f(u.w), wv, acc.w);
    }
    ushort4 u = hp[(size_t)r * 64 + lane];
    float wd = di * di;
    acc.x = fmaf(bf2f(u.x), wd, acc.x);
    acc.y = fmaf(bf2f(u.y), wd, acc.y);
    acc.z = fmaf(bf2f(u.z), wd, acc.z);
    acc.w = fmaf(bf2f(u.w), wd, acc.w);
    ((float4*)t1p)[(size_t)p * 64 + lane] = acc;
}

// ------- MFMA GEMM layer 1 (post rows): accP += t1p @ W2 + b2 + h[post] -------
__global__ __launch_bounds__(256) void gemm_l1_mfma(const float* __restrict__ A,
        const float* __restrict__ B, const float* __restrict__ b2,
        const unsigned short* __restrict__ h, const int* __restrict__ post,
        float* __restrict__ accP, int M) {
    __shared__ unsigned short As[64][136];
    __shared__ unsigned short Bs[64][136];
    int tid = threadIdx.x;
    int m0 = blockIdx.x * 64, n0 = blockIdx.y * 64;
    int w = tid >> 6, l = tid & 63;
    int q = l >> 4, mrow = l & 15;
    f32x4 acc[4] = {{0.f,0.f,0.f,0.f},{0.f,0.f,0.f,0.f},{0.f,0.f,0.f,0.f},{0.f,0.f,0.f,0.f}};
    for (int kk = 0; kk < 256; kk += 128) {
        __syncthreads();
        {
            int row = tid >> 2, c0 = (tid & 3) * 32;
            int gm = m0 + row;
            #pragma unroll
            for (int i = 0; i < 8; ++i) {
                float4 v = make_float4(0.f, 0.f, 0.f, 0.f);
                if (gm < M) v = *(const float4*)(A + (size_t)gm * 256 + kk + c0 + i * 4);
                As[row][c0 + i * 4 + 0] = f2bf(v.x);
                As[row][c0 + i * 4 + 1] = f2bf(v.y);
                As[row][c0 + i * 4 + 2] = f2bf(v.z);
                As[row][c0 + i * 4 + 3] = f2bf(v.w);
            }
        }
        {
            int k = tid >> 1, nb = (tid & 1) * 32;
            #pragma unroll
            for (int i = 0; i < 8; ++i) {
                float4 v = *(const float4*)(B + (size_t)(kk + k) * H_DIM + n0 + nb + i * 4);
                Bs[nb + i * 4 + 0][k] = f2bf(v.x);
                Bs[nb + i * 4 + 1][k] = f2bf(v.y);
                Bs[nb + i * 4 + 2][k] = f2bf(v.z);
                Bs[nb + i * 4 + 3][k] = f2bf(v.w);
            }
        }
        __syncthreads();
        #pragma unroll
        for (int ks = 0; ks < 4; ++ks) {
            bf16x8 a = *(const bf16x8*)&As[16 * w + mrow][ks * 32 + q * 8];
            #pragma unroll
            for (int ct = 0; ct < 4; ++ct) {
                bf16x8 b = *(const bf16x8*)&Bs[ct * 16 + mrow][ks * 32 + q * 8];
                acc[ct] = __builtin_amdgcn_mfma_f32_16x16x32_bf16(a, b, acc[ct], 0, 0, 0);
            }
        }
    }
    #pragma unroll
    for (int ct = 0; ct < 4; ++ct) {
        int col = n0 + ct * 16 + mrow;
        float bias = b2[col];
        #pragma unroll
        for (int i = 0; i < 4; ++i) {
            int m = m0 + 16 * w + q * 4 + i;
            if (m < M) {
                int node = post[m];
                float hv = bf2f(h[(size_t)node * 256 + col]);
                accP[(size_t)m * 256 + col] += acc[ct][i] + bias + hv;
            }
        }
    }
}

// ---------------- classifier ----------------
__global__ __launch_bounds__(128) void classifier_kernel(const float* __restrict__ accP,
        const float* __restrict__ Wc1, const float* __restrict__ bc1,
        const float* __restrict__ Wc2, const float* __restrict__ bc2,
        float* __restrict__ out) {
    __shared__ float arow[8][256];
    __shared__ float red[2][8];
    int p0 = blockIdx.x << 3;
    int tid = threadIdx.x;
    for (int idx = tid; idx < 8 * 256; idx += 128) {
        int pl = idx >> 8, k = idx & 255;
        arow[pl][k] = 0.25f * accP[(size_t)(p0 + pl) * 256 + k];
    }
    __syncthreads();
    float s[8];
    float b = bc1[tid];
    #pragma unroll
    for (int pl = 0; pl < 8; ++pl) s[pl] = b;
    for (int k = 0; k < 256; ++k) {
        float wv = Wc1[k * 128 + tid];
        #pragma unroll
        for (int pl = 0; pl < 8; ++pl) s[pl] = fmaf(arow[pl][k], wv, s[pl]);
    }
    float wc2 = Wc2[tid];
    float part[8];
    #pragma unroll
    for (int pl = 0; pl < 8; ++pl) part[pl] = fmaxf(s[pl], 0.f) * wc2;
    #pragma unroll
    for (int off = 32; off > 0; off >>= 1)
        #pragma unroll
        for (int pl = 0; pl < 8; ++pl) part[pl] += __shfl_down(part[pl], off, 64);
    int wave = tid >> 6, lane = tid & 63;
    if (lane == 0) {
        #pragma unroll
        for (int pl = 0; pl < 8; ++pl) red[wave][pl] = part[pl];
    }
    __syncthreads();
    if (tid < 8) {
        float logit = red[0][tid] + red[1][tid] + bc2[0];
        out[p0 + tid] = 1.f / (1.f + expf(-logit));
    }
}

extern "C" void kernel_launch(void* const* d_in, const int* in_sizes, int n_in,
                              void* d_out, int out_size, void* d_ws, size_t ws_size,
                              hipStream_t stream) {
    const float* x   = (const float*)d_in[0];
    const int*   ei  = (const int*)d_in[1];
    const int*   post= (const int*)d_in[2];
    const float* W1  = (const float*)d_in[3];
    const float* b1  = (const float*)d_in[4];
    const float* W2  = (const float*)d_in[5];
    const float* b2  = (const float*)d_in[6];
    const float* Wc1 = (const float*)d_in[7];
    const float* bc1 = (const float*)d_in[8];
    const float* Wc2 = (const float*)d_in[9];
    const float* bc2 = (const float*)d_in[10];
    float* out = (float*)d_out;

    char* w = (char*)d_ws;
    size_t off = 0;
#define WS_ALLOC(type, name, count) \
    type* name = (type*)(w + off); \
    off += (((size_t)(count) * sizeof(type)) + 255) & ~(size_t)255;
    WS_ALLOC(unsigned short, xw1,     (size_t)N_NODES * H_DIM)   // 51.2 MB (bf16)
    WS_ALLOC(unsigned short, hbuf,    (size_t)N_NODES * H_DIM)   // 51.2 MB (counts aliases)
    WS_ALLOC(float,          t1p,     (size_t)P_POST * H_DIM)    // 10.24 MB
    WS_ALLOC(float,          accP,    (size_t)P_POST * H_DIM)    // 10.24 MB
    WS_ALLOC(int,            deg4,    N4)                        // 1.6 MB
    WS_ALLOC(float,          dinv4,   N4)                        // 1.6 MB
    WS_ALLOC(int,            rowptr4, N4 + 4)                    // 1.6 MB
    WS_ALLOC(int,            csrsrc4, E4)                        // 25.6 MB
    WS_ALLOC(int,            bsum,    NBLK4)
    WS_ALLOC(int,            boff,    NBLK4)
#undef WS_ALLOC
    // counts/chunkbase [512][12500] (25.6 MB) aliases hbuf: dead before spmm_l0 writes h
    int* counts = (int*)hbuf;                        // total ws ~153 MB
    (void)ws_size; (void)in_sizes; (void)n_in; (void)out_size;

    zero32_kernel<<<(P_POST * H_DIM + 255) / 256, 256, 0, stream>>>(
        (unsigned int*)accP, P_POST * H_DIM);

    // ---- atomic-free batched CSR build for all 4 snapshots ----
    count_kernel<<<PREP_BLOCKS, 256, 0, stream>>>(ei, counts);
    chunkprefix_kernel<<<S_SNAP * NBIN * 4, 256, 0, stream>>>(counts, deg4);
    scan_part4_kernel<<<NBLK4, 256, 0, stream>>>(deg4, bsum, dinv4);
    scan_top_kernel<<<1, 512, 0, stream>>>(bsum, boff);
    scan_fin4_kernel<<<NBLK4, 256, 0, stream>>>(deg4, boff, rowptr4);
    fillb_kernel<<<PREP_BLOCKS, 256, 0, stream>>>(ei, counts, rowptr4, csrsrc4);

    // xw1 = x @ W1 once per call (snapshot-invariant) — bf16 MFMA
    dim3 gg((N_NODES + 63) / 64, H_DIM / 64);
    gemm_xw1_mfma<<<gg, 256, 0, stream>>>(x, W1, xw1, N_NODES);

    for (int s = 0; s < S_SNAP; ++s) {
        int soff = s * N_NODES;
        // h = relu(Ahat @ xw1 + b1)   [N,256] bf16   (overwrites counts region — dead)
        spmm_l0_kernel<<<N_NODES / 4, 256, 0, stream>>>(xw1, dinv4, rowptr4, csrsrc4,
                                                        b1, hbuf, soff);
        // t1p = (Ahat @ h)[post]   [P,256] fp32
        spmm_h_post_kernel<<<P_POST / 4, 256, 0, stream>>>(hbuf, dinv4, rowptr4, csrsrc4,
                                                           post, t1p, soff);
        // accP += t1p @ W2 + b2 + h[post]   — bf16 MFMA
        dim3 g1((P_POST + 63) / 64, H_DIM / 64);
        gemm_l1_mfma<<<g1, 256, 0, stream>>>(t1p, W2, b2, hbuf, post, accP, P_POST);
    }
    classifier_kernel<<<P_POST / 8, 128, 0, stream>>>(accP, Wc1, bc1, Wc2, bc2, out);
}

// Round 12
// 1221.491 us; speedup vs baseline: 1.2093x; 1.2093x over previous
//
#include <hip/hip_runtime.h>
#include <math.h>

#define N_NODES 100000
#define E_EDGES 1600000
#define S_SNAP  4
#define D_IN    128
#define H_DIM   256
#define P_POST  10000
#define N4 (S_SNAP * N_NODES)               // 400000
#define E4 (S_SNAP * E_EDGES)               // 6400000
#define NBLK4 ((N4 + 1023) / 1024)          // 391
#define NBIN 8
#define BIN_W (N_NODES / NBIN)              // 12500
#define FILL_CHUNK 2048
#define FILL_NCHUNK ((E4 + FILL_CHUNK - 1) / FILL_CHUNK)   // 3125

typedef __attribute__((ext_vector_type(8))) short bf16x8;   // MFMA A/B frag (4 VGPRs)
typedef __attribute__((ext_vector_type(4))) float f32x4;    // MFMA C/D frag

// ---------- bf16 helpers ----------
__device__ __forceinline__ float bf2f(unsigned short u) {
    union { unsigned int i; float f; } v; v.i = ((unsigned int)u) << 16; return v.f;
}
__device__ __forceinline__ unsigned short f2bf(float f) {
    union { float f; unsigned int i; } v; v.f = f;
    unsigned int lsb = (v.i >> 16) & 1u;
    v.i += 0x7fffu + lsb;                 // round-nearest-even
    return (unsigned short)(v.i >> 16);
}

// ---------------- utility ----------------
__global__ void zero32_kernel(unsigned int* __restrict__ p, int n) {
    int i = blockIdx.x * blockDim.x + threadIdx.x;
    if (i < n) p[i] = 0u;
}

// ---------------- batched graph prep (r10-proven) ----------------
__global__ void hist4_kernel(const int* __restrict__ ei, int* __restrict__ deg4,
        int* __restrict__ slot4) {
    int i = blockIdx.x * 256 + threadIdx.x;          // grid covers E4 exactly
    int s = i / E_EDGES;
    int j = i - s * E_EDGES;
    int d = ei[(size_t)s * 2 * E_EDGES + E_EDGES + j];
    slot4[i] = atomicAdd(&deg4[s * N_NODES + d], 1);
}

__global__ __launch_bounds__(256) void scan_part4_kernel(const int* __restrict__ deg4,
        int* __restrict__ bsum, float* __restrict__ dinv4) {
    __shared__ int red[4];
    int base = blockIdx.x * 1024 + threadIdx.x * 4;
    int4 v = make_int4(0, 0, 0, 0);
    if (base < N4) {
        v = *(const int4*)(deg4 + base);
        dinv4[base + 0] = rsqrtf((float)(v.x + 1));   // +1 self-loop
        dinv4[base + 1] = rsqrtf((float)(v.y + 1));
        dinv4[base + 2] = rsqrtf((float)(v.z + 1));
        dinv4[base + 3] = rsqrtf((float)(v.w + 1));
    }
    int t = v.x + v.y + v.z + v.w;
    #pragma unroll
    for (int off = 32; off > 0; off >>= 1) t += __shfl_down(t, off, 64);
    int wave = threadIdx.x >> 6, lane = threadIdx.x & 63;
    if (lane == 0) red[wave] = t;
    __syncthreads();
    if (threadIdx.x == 0) bsum[blockIdx.x] = red[0] + red[1] + red[2] + red[3];
}

__global__ __launch_bounds__(512) void scan_top_kernel(const int* __restrict__ bsum,
        int* __restrict__ boff) {
    __shared__ int s[512];
    int t = threadIdx.x;
    s[t] = (t < NBLK4) ? bsum[t] : 0;
    __syncthreads();
    for (int off = 1; off < 512; off <<= 1) {
        int v = (t >= off) ? s[t - off] : 0;
        __syncthreads();
        s[t] += v;
        __syncthreads();
    }
    if (t < NBLK4) boff[t] = (t == 0) ? 0 : s[t - 1];
}

__global__ __launch_bounds__(256) void scan_fin4_kernel(const int* __restrict__ deg4,
        const int* __restrict__ boff, int* __restrict__ rowptr4) {
    __shared__ int sh[256];
    int base = blockIdx.x * 1024 + threadIdx.x * 4;
    int4 v = make_int4(0, 0, 0, 0);
    if (base < N4) v = *(const int4*)(deg4 + base);
    int tsum = v.x + v.y + v.z + v.w;
    sh[threadIdx.x] = tsum;
    __syncthreads();
    for (int off = 1; off < 256; off <<= 1) {
        int u = (threadIdx.x >= off) ? sh[threadIdx.x - off] : 0;
        __syncthreads();
        sh[threadIdx.x] += u;
        __syncthreads();
    }
    int excl = boff[blockIdx.x] + sh[threadIdx.x] - tsum;
    if (base < N4) {
        int4 o;
        o.x = excl;
        o.y = excl + v.x;
        o.z = excl + v.x + v.y;
        o.w = excl + v.x + v.y + v.z;
        *(int4*)(rowptr4 + base) = o;
    }
    if (base == 0) rowptr4[N4] = E4;
}

// binned, atomic-free CSR fill over all 4E edges (r10-proven: bin regions L2-resident)
__global__ __launch_bounds__(256) void fill4_kernel(const int* __restrict__ ei,
        const int* __restrict__ slot4, const int* __restrict__ rowptr4,
        int* __restrict__ csrsrc4) {
    int chunk = blockIdx.x >> 3;
    int bin = blockIdx.x & (NBIN - 1);
    int lo = bin * BIN_W, hi = lo + BIN_W;
    int base = chunk * FILL_CHUNK + threadIdx.x;
    #pragma unroll
    for (int k = 0; k < FILL_CHUNK / 256; ++k) {
        int i = base + k * 256;
        if (i < E4) {
            int s = i / E_EDGES;
            int j = i - s * E_EDGES;
            int d = ei[(size_t)s * 2 * E_EDGES + E_EDGES + j];
            if (d >= lo && d < hi) {
                int sc = ei[(size_t)s * 2 * E_EDGES + j];
                csrsrc4[rowptr4[s * N_NODES + d] + slot4[i]] = sc;
            }
        }
    }
}

// ------- MFMA GEMM (once per call): xw1 = x @ W1, bf16 out -------
// Layouts (HW-verified r8): A[m=lane&15][k=quad*8+j]; B[k][n=lane&15]; C/D col=lane&15,row=quad*4+reg
__global__ __launch_bounds__(256) void gemm_xw1_mfma(const float* __restrict__ A,
        const float* __restrict__ B, unsigned short* __restrict__ C, int M) {
    __shared__ unsigned short As[64][136];   // [m][k], +8 pad
    __shared__ unsigned short Bs[64][136];   // [n][k]
    int tid = threadIdx.x;
    int m0 = blockIdx.x * 64, n0 = blockIdx.y * 64;
    {
        int row = tid >> 2, c0 = (tid & 3) * 32;
        int gm = m0 + row;
        #pragma unroll
        for (int i = 0; i < 8; ++i) {
            float4 v = make_float4(0.f, 0.f, 0.f, 0.f);
            if (gm < M) v = *(const float4*)(A + (size_t)gm * D_IN + c0 + i * 4);
            As[row][c0 + i * 4 + 0] = f2bf(v.x);
            As[row][c0 + i * 4 + 1] = f2bf(v.y);
            As[row][c0 + i * 4 + 2] = f2bf(v.z);
            As[row][c0 + i * 4 + 3] = f2bf(v.w);
        }
    }
    {
        int k = tid >> 1, nb = (tid & 1) * 32;
        #pragma unroll
        for (int i = 0; i < 8; ++i) {
            float4 v = *(const float4*)(B + (size_t)k * H_DIM + n0 + nb + i * 4);
            Bs[nb + i * 4 + 0][k] = f2bf(v.x);
            Bs[nb + i * 4 + 1][k] = f2bf(v.y);
            Bs[nb + i * 4 + 2][k] = f2bf(v.z);
            Bs[nb + i * 4 + 3][k] = f2bf(v.w);
        }
    }
    __syncthreads();
    int w = tid >> 6, l = tid & 63;
    int q = l >> 4, mrow = l & 15;
    f32x4 acc[4] = {{0.f,0.f,0.f,0.f},{0.f,0.f,0.f,0.f},{0.f,0.f,0.f,0.f},{0.f,0.f,0.f,0.f}};
    #pragma unroll
    for (int kk = 0; kk < 4; ++kk) {
        bf16x8 a = *(const bf16x8*)&As[16 * w + mrow][kk * 32 + q * 8];
        #pragma unroll
        for (int ct = 0; ct < 4; ++ct) {
            bf16x8 b = *(const bf16x8*)&Bs[ct * 16 + mrow][kk * 32 + q * 8];
            acc[ct] = __builtin_amdgcn_mfma_f32_16x16x32_bf16(a, b, acc[ct], 0, 0, 0);
        }
    }
    #pragma unroll
    for (int ct = 0; ct < 4; ++ct) {
        int col = n0 + ct * 16 + mrow;
        #pragma unroll
        for (int i = 0; i < 4; ++i) {
            int m = m0 + 16 * w + q * 4 + i;
            if (m < M) C[(size_t)m * H_DIM + col] = f2bf(acc[ct][i]);
        }
    }
}

// ------- SpMM layer 0 (fused bias+relu), 4-way edge unroll (r7/r9-proven: VGPR 20) -------
__global__ __launch_bounds__(256) void spmm_l0_kernel(const unsigned short* __restrict__ xw1,
        const float* __restrict__ dinv4, const int* __restrict__ rowptr4,
        const int* __restrict__ csrsrc4, const float* __restrict__ b1,
        unsigned short* __restrict__ h, int soff) {
    int r = (blockIdx.x << 2) + (threadIdx.x >> 6);
    int lane = threadIdx.x & 63;
    int rg = soff + r;
    int e0 = rowptr4[rg], e1 = rowptr4[rg + 1];
    float di = dinv4[rg];
    float4 acc = make_float4(0.f, 0.f, 0.f, 0.f);
    const ushort4* tp = (const ushort4*)xw1;
    const float* dv = dinv4 + soff;
    int e = e0;
    for (; e + 4 <= e1; e += 4) {
        int s0 = csrsrc4[e], s1 = csrsrc4[e + 1], s2 = csrsrc4[e + 2], s3 = csrsrc4[e + 3];
        float w0 = dv[s0] * di, w1 = dv[s1] * di, w2 = dv[s2] * di, w3 = dv[s3] * di;
        ushort4 u0 = tp[(size_t)s0 * 64 + lane];
        ushort4 u1 = tp[(size_t)s1 * 64 + lane];
        ushort4 u2 = tp[(size_t)s2 * 64 + lane];
        ushort4 u3 = tp[(size_t)s3 * 64 + lane];
        acc.x = fmaf(bf2f(u0.x), w0, acc.x); acc.y = fmaf(bf2f(u0.y), w0, acc.y);
        acc.z = fmaf(bf2f(u0.z), w0, acc.z); acc.w = fmaf(bf2f(u0.w), w0, acc.w);
        acc.x = fmaf(bf2f(u1.x), w1, acc.x); acc.y = fmaf(bf2f(u1.y), w1, acc.y);
        acc.z = fmaf(bf2f(u1.z), w1, acc.z); acc.w = fmaf(bf2f(u1.w), w1, acc.w);
        acc.x = fmaf(bf2f(u2.x), w2, acc.x); acc.y = fmaf(bf2f(u2.y), w2, acc.y);
        acc.z = fmaf(bf2f(u2.z), w2, acc.z); acc.w = fmaf(bf2f(u2.w), w2, acc.w);
        acc.x = fmaf(bf2f(u3.x), w3, acc.x); acc.y = fmaf(bf2f(u3.y), w3, acc.y);
        acc.z = fmaf(bf2f(u3.z), w3, acc.z); acc.w = fmaf(bf2f(u3.w), w3, acc.w);
    }
    for (; e < e1; ++e) {
        int s = csrsrc4[e];
        float wv = dv[s] * di;
        ushort4 u = tp[(size_t)s * 64 + lane];
        acc.x = fmaf(bf2f(u.x), wv, acc.x); acc.y = fmaf(bf2f(u.y), wv, acc.y);
        acc.z = fmaf(bf2f(u.z), wv, acc.z); acc.w = fmaf(bf2f(u.w), wv, acc.w);
    }
    ushort4 us = tp[(size_t)r * 64 + lane];
    float wd = di * di;
    float4 bb = ((const float4*)b1)[lane];
    ushort4 o;
    o.x = f2bf(fmaxf(fmaf(bf2f(us.x), wd, acc.x) + bb.x, 0.f));
    o.y = f2bf(fmaxf(fmaf(bf2f(us.y), wd, acc.y) + bb.y, 0.f));
    o.z = f2bf(fmaxf(fmaf(bf2f(us.z), wd, acc.z) + bb.z, 0.f));
    o.w = f2bf(fmaxf(fmaf(bf2f(us.w), wd, acc.w) + bb.w, 0.f));
    ((ushort4*)h)[(size_t)r * 64 + lane] = o;
}

// --- SpMM layer 1 (post rows), accumulating across snapshots:
//     t1acc[p] (+)= (Ahat_s @ h_s)[post[p]],  hacc[p] (+)= h_s[post[p]]  (self row is free)
__global__ __launch_bounds__(256) void spmm_h_post_kernel(const unsigned short* __restrict__ h,
        const float* __restrict__ dinv4, const int* __restrict__ rowptr4,
        const int* __restrict__ csrsrc4, const int* __restrict__ post,
        float* __restrict__ t1acc, float* __restrict__ hacc, int soff, int first) {
    int p = (blockIdx.x << 2) + (threadIdx.x >> 6);
    int lane = threadIdx.x & 63;
    int r = post[p];
    int rg = soff + r;
    int e0 = rowptr4[rg], e1 = rowptr4[rg + 1];
    float di = dinv4[rg];
    float4 acc = make_float4(0.f, 0.f, 0.f, 0.f);
    const ushort4* hp = (const ushort4*)h;
    const float* dv = dinv4 + soff;
    int e = e0;
    for (; e + 4 <= e1; e += 4) {
        int s0 = csrsrc4[e], s1 = csrsrc4[e + 1], s2 = csrsrc4[e + 2], s3 = csrsrc4[e + 3];
        float w0 = dv[s0] * di, w1 = dv[s1] * di, w2 = dv[s2] * di, w3 = dv[s3] * di;
        ushort4 u0 = hp[(size_t)s0 * 64 + lane];
        ushort4 u1 = hp[(size_t)s1 * 64 + lane];
        ushort4 u2 = hp[(size_t)s2 * 64 + lane];
        ushort4 u3 = hp[(size_t)s3 * 64 + lane];
        acc.x = fmaf(bf2f(u0.x), w0, acc.x); acc.y = fmaf(bf2f(u0.y), w0, acc.y);
        acc.z = fmaf(bf2f(u0.z), w0, acc.z); acc.w = fmaf(bf2f(u0.w), w0, acc.w);
        acc.x = fmaf(bf2f(u1.x), w1, acc.x); acc.y = fmaf(bf2f(u1.y), w1, acc.y);
        acc.z = fmaf(bf2f(u1.z), w1, acc.z); acc.w = fmaf(bf2f(u1.w), w1, acc.w);
        acc.x = fmaf(bf2f(u2.x), w2, acc.x); acc.y = fmaf(bf2f(u2.y), w2, acc.y);
        acc.z = fmaf(bf2f(u2.z), w2, acc.z); acc.w = fmaf(bf2f(u2.w), w2, acc.w);
        acc.x = fmaf(bf2f(u3.x), w3, acc.x); acc.y = fmaf(bf2f(u3.y), w3, acc.y);
        acc.z = fmaf(bf2f(u3.z), w3, acc.z); acc.w = fmaf(bf2f(u3.w), w3, acc.w);
    }
    for (; e < e1; ++e) {
        int s = csrsrc4[e];
        float wv = dv[s] * di;
        ushort4 u = hp[(size_t)s * 64 + lane];
        acc.x = fmaf(bf2f(u.x), wv, acc.x); acc.y = fmaf(bf2f(u.y), wv, acc.y);
        acc.z = fmaf(bf2f(u.z), wv, acc.z); acc.w = fmaf(bf2f(u.w), wv, acc.w);
    }
    ushort4 u = hp[(size_t)r * 64 + lane];        // self row = h_s[post[p]]
    float hx = bf2f(u.x), hy = bf2f(u.y), hz = bf2f(u.z), hw = bf2f(u.w);
    float wd = di * di;
    acc.x = fmaf(hx, wd, acc.x);
    acc.y = fmaf(hy, wd, acc.y);
    acc.z = fmaf(hz, wd, acc.z);
    acc.w = fmaf(hw, wd, acc.w);
    size_t idx = (size_t)p * 64 + lane;
    float4 hv = make_float4(hx, hy, hz, hw);
    if (first) {
        ((float4*)t1acc)[idx] = acc;
        ((float4*)hacc)[idx] = hv;
    } else {
        float4 a = ((float4*)t1acc)[idx];
        a.x += acc.x; a.y += acc.y; a.z += acc.z; a.w += acc.w;
        ((float4*)t1acc)[idx] = a;
        float4 b = ((float4*)hacc)[idx];
        b.x += hv.x; b.y += hv.y; b.z += hv.z; b.w += hv.w;
        ((float4*)hacc)[idx] = b;
    }
}

// ------- MFMA GEMM layer 1 (ONCE): accP = t1acc @ W2 + 4*b2 + hacc -------
__global__ __launch_bounds__(256) void gemm_l1_mfma(const float* __restrict__ A,
        const float* __restrict__ B, const float* __restrict__ b2,
        const float* __restrict__ hacc, float* __restrict__ accP, int M) {
    __shared__ unsigned short As[64][136];
    __shared__ unsigned short Bs[64][136];
    int tid = threadIdx.x;
    int m0 = blockIdx.x * 64, n0 = blockIdx.y * 64;
    int w = tid >> 6, l = tid & 63;
    int q = l >> 4, mrow = l & 15;
    f32x4 acc[4] = {{0.f,0.f,0.f,0.f},{0.f,0.f,0.f,0.f},{0.f,0.f,0.f,0.f},{0.f,0.f,0.f,0.f}};
    for (int kk = 0; kk < 256; kk += 128) {
        __syncthreads();
        {
            int row = tid >> 2, c0 = (tid & 3) * 32;
            int gm = m0 + row;
            #pragma unroll
            for (int i = 0; i < 8; ++i) {
                float4 v = make_float4(0.f, 0.f, 0.f, 0.f);
                if (gm < M) v = *(const float4*)(A + (size_t)gm * 256 + kk + c0 + i * 4);
                As[row][c0 + i * 4 + 0] = f2bf(v.x);
                As[row][c0 + i * 4 + 1] = f2bf(v.y);
                As[row][c0 + i * 4 + 2] = f2bf(v.z);
                As[row][c0 + i * 4 + 3] = f2bf(v.w);
            }
        }
        {
            int k = tid >> 1, nb = (tid & 1) * 32;
            #pragma unroll
            for (int i = 0; i < 8; ++i) {
                float4 v = *(const float4*)(B + (size_t)(kk + k) * H_DIM + n0 + nb + i * 4);
                Bs[nb + i * 4 + 0][k] = f2bf(v.x);
                Bs[nb + i * 4 + 1][k] = f2bf(v.y);
                Bs[nb + i * 4 + 2][k] = f2bf(v.z);
                Bs[nb + i * 4 + 3][k] = f2bf(v.w);
            }
        }
        __syncthreads();
        #pragma unroll
        for (int ks = 0; ks < 4; ++ks) {
            bf16x8 a = *(const bf16x8*)&As[16 * w + mrow][ks * 32 + q * 8];
            #pragma unroll
            for (int ct = 0; ct < 4; ++ct) {
                bf16x8 b = *(const bf16x8*)&Bs[ct * 16 + mrow][ks * 32 + q * 8];
                acc[ct] = __builtin_amdgcn_mfma_f32_16x16x32_bf16(a, b, acc[ct], 0, 0, 0);
            }
        }
    }
    #pragma unroll
    for (int ct = 0; ct < 4; ++ct) {
        int col = n0 + ct * 16 + mrow;
        float bias = 4.0f * b2[col];
        #pragma unroll
        for (int i = 0; i < 4; ++i) {
            int m = m0 + 16 * w + q * 4 + i;
            if (m < M) {
                accP[(size_t)m * 256 + col] =
                    acc[ct][i] + bias + hacc[(size_t)m * 256 + col];
            }
        }
    }
}

// ---------------- classifier ----------------
__global__ __launch_bounds__(128) void classifier_kernel(const float* __restrict__ accP,
        const float* __restrict__ Wc1, const float* __restrict__ bc1,
        const float* __restrict__ Wc2, const float* __restrict__ bc2,
        float* __restrict__ out) {
    __shared__ float arow[8][256];
    __shared__ float red[2][8];
    int p0 = blockIdx.x << 3;
    int tid = threadIdx.x;
    for (int idx = tid; idx < 8 * 256; idx += 128) {
        int pl = idx >> 8, k = idx & 255;
        arow[pl][k] = 0.25f * accP[(size_t)(p0 + pl) * 256 + k];
    }
    __syncthreads();
    float s[8];
    float b = bc1[tid];
    #pragma unroll
    for (int pl = 0; pl < 8; ++pl) s[pl] = b;
    for (int k = 0; k < 256; ++k) {
        float wv = Wc1[k * 128 + tid];
        #pragma unroll
        for (int pl = 0; pl < 8; ++pl) s[pl] = fmaf(arow[pl][k], wv, s[pl]);
    }
    float wc2 = Wc2[tid];
    float part[8];
    #pragma unroll
    for (int pl = 0; pl < 8; ++pl) part[pl] = fmaxf(s[pl], 0.f) * wc2;
    #pragma unroll
    for (int off = 32; off > 0; off >>= 1)
        #pragma unroll
        for (int pl = 0; pl < 8; ++pl) part[pl] += __shfl_down(part[pl], off, 64);
    int wave = tid >> 6, lane = tid & 63;
    if (lane == 0) {
        #pragma unroll
        for (int pl = 0; pl < 8; ++pl) red[wave][pl] = part[pl];
    }
    __syncthreads();
    if (tid < 8) {
        float logit = red[0][tid] + red[1][tid] + bc2[0];
        out[p0 + tid] = 1.f / (1.f + expf(-logit));
    }
}

extern "C" void kernel_launch(void* const* d_in, const int* in_sizes, int n_in,
                              void* d_out, int out_size, void* d_ws, size_t ws_size,
                              hipStream_t stream) {
    const float* x   = (const float*)d_in[0];
    const int*   ei  = (const int*)d_in[1];
    const int*   post= (const int*)d_in[2];
    const float* W1  = (const float*)d_in[3];
    const float* b1  = (const float*)d_in[4];
    const float* W2  = (const float*)d_in[5];
    const float* b2  = (const float*)d_in[6];
    const float* Wc1 = (const float*)d_in[7];
    const float* bc1 = (const float*)d_in[8];
    const float* Wc2 = (const float*)d_in[9];
    const float* bc2 = (const float*)d_in[10];
    float* out = (float*)d_out;

    char* w = (char*)d_ws;
    size_t off = 0;
#define WS_ALLOC(type, name, count) \
    type* name = (type*)(w + off); \
    off += (((size_t)(count) * sizeof(type)) + 255) & ~(size_t)255;
    WS_ALLOC(unsigned short, xw1,     (size_t)N_NODES * H_DIM)   // 51.2 MB (accP aliases)
    WS_ALLOC(unsigned short, hbuf,    (size_t)N_NODES * H_DIM)   // 51.2 MB (slot4 aliases)
    WS_ALLOC(float,          t1acc,   (size_t)P_POST * H_DIM)    // 10.24 MB
    WS_ALLOC(float,          hacc,    (size_t)P_POST * H_DIM)    // 10.24 MB
    WS_ALLOC(int,            deg4,    N4)                        // 1.6 MB
    WS_ALLOC(float,          dinv4,   N4)                        // 1.6 MB
    WS_ALLOC(int,            rowptr4, N4 + 4)                    // 1.6 MB
    WS_ALLOC(int,            csrsrc4, E4)                        // 25.6 MB
    WS_ALLOC(int,            bsum,    NBLK4)
    WS_ALLOC(int,            boff,    NBLK4)
#undef WS_ALLOC
    // slot4[E4] (25.6 MB) aliases hbuf: dead before spmm_l0 writes h        (r10-proven)
    // accP [P,256] fp32 (10.24 MB) aliases xw1: xw1 dead after last spmm_l0 (new)
    int* slot4 = (int*)hbuf;
    float* accP = (float*)xw1;                       // total ws ~153 MB (r10 level)
    (void)ws_size; (void)in_sizes; (void)n_in; (void)out_size;

    // only deg4 needs zero-init (hist4 atomics); accumulators use first-flag stores
    zero32_kernel<<<(N4 + 255) / 256, 256, 0, stream>>>((unsigned int*)deg4, N4);

    // ---- batched prep for all 4 snapshots (r10-proven path) ----
    hist4_kernel<<<E4 / 256, 256, 0, stream>>>(ei, deg4, slot4);
    scan_part4_kernel<<<NBLK4, 256, 0, stream>>>(deg4, bsum, dinv4);
    scan_top_kernel<<<1, 512, 0, stream>>>(bsum, boff);
    scan_fin4_kernel<<<NBLK4, 256, 0, stream>>>(deg4, boff, rowptr4);
    fill4_kernel<<<FILL_NCHUNK * NBIN, 256, 0, stream>>>(ei, slot4, rowptr4, csrsrc4);

    // xw1 = x @ W1 once per call (snapshot-invariant) — bf16 MFMA
    dim3 gg((N_NODES + 63) / 64, H_DIM / 64);
    gemm_xw1_mfma<<<gg, 256, 0, stream>>>(x, W1, xw1, N_NODES);

    for (int s = 0; s < S_SNAP; ++s) {
        int soff = s * N_NODES;
        // h = relu(Ahat @ xw1 + b1)   [N,256] bf16   (overwrites slot4 region — dead)
        spmm_l0_kernel<<<N_NODES / 4, 256, 0, stream>>>(xw1, dinv4, rowptr4, csrsrc4,
                                                        b1, hbuf, soff);
        // t1acc (+)= (Ahat @ h)[post];  hacc (+)= h[post]
        spmm_h_post_kernel<<<P_POST / 4, 256, 0, stream>>>(hbuf, dinv4, rowptr4, csrsrc4,
                                                           post, t1acc, hacc, soff, s == 0);
    }
    // accP = t1acc @ W2 + 4*b2 + hacc   — single bf16 MFMA GEMM (W2 snapshot-invariant)
    dim3 g1((P_POST + 63) / 64, H_DIM / 64);
    gemm_l1_mfma<<<g1, 256, 0, stream>>>(t1acc, W2, b2, hacc, accP, P_POST);

    classifier_kernel<<<P_POST / 8, 128, 0, stream>>>(accP, Wc1, bc1, Wc2, bc2, out);
}